// Round 1
// baseline (197.633 us; speedup 1.0000x reference)
//
#include <hip/hip_runtime.h>
#include <cmath>

#define T_LEN 262144
#define NROW 8
#define NL 30
#define TILE 3520
#define HALO 576
#define EXT (TILE + HALO)          /* 4096 */
#define NT 256
#define PPT (EXT / NT)             /* 16 positions per thread */
#define PB ((T_LEN + TILE - 1) / TILE)   /* 75 tiles per row */
#define CH 4096                    /* elements per softmax block */
#define RB (T_LEN / CH)            /* 64 softmax blocks per row */
#define NB2 (NROW * RB)            /* 512 */

__device__ const int c_dil[NL] = {1,2,4,8,6,2,4,8,6,2,4,8,6,2,4,8,6,2,4,8,6,2,4,8,6,2,4,8,6,2};

__device__ __forceinline__ float fast_rcp(float x) { return __builtin_amdgcn_rcpf(x); }

// ---------------------------------------------------------------------------
// K1: fused 30-layer WaveNet over a time tile with halo; writes pre-softmax
// value v into vout and the per-block max into partmax[blockIdx].
// ---------------------------------------------------------------------------
__global__ __launch_bounds__(NT)
void k_wavenet(const float* __restrict__ x,
               const float* __restrict__ cw,  const float* __restrict__ cb,
               const float* __restrict__ fw,  const float* __restrict__ fb,
               const float* __restrict__ gw,  const float* __restrict__ gb,
               const float* __restrict__ rw,  const float* __restrict__ rb,
               const float* __restrict__ c1w, const float* __restrict__ c1b,
               const float* __restrict__ c2w, const float* __restrict__ c2b,
               float* __restrict__ vout, float* __restrict__ partmax)
{
    __shared__ float hbuf[EXT];        // 16 KB
    __shared__ float wbuf[NL * 14];    // per-layer weights
    __shared__ float cwb[10];          // causal conv + output 1x1s
    __shared__ float redm[NT / 64];

    const int tid  = threadIdx.x;
    const int row  = blockIdx.x / PB;
    const int tile = blockIdx.x % PB;
    const int t0   = tile * TILE;

    // cooperative weight preload (before first barrier)
    if (tid < NL) {
        const int k = tid;
        #pragma unroll
        for (int j = 0; j < 5; ++j) wbuf[k*14 + j]     = fw[k*5 + j];
        wbuf[k*14 + 5]  = fb[k];
        #pragma unroll
        for (int j = 0; j < 5; ++j) wbuf[k*14 + 6 + j] = gw[k*5 + j];
        wbuf[k*14 + 11] = gb[k];
        wbuf[k*14 + 12] = rw[k];
        wbuf[k*14 + 13] = rb[k];
    } else if (tid == NL) {
        #pragma unroll
        for (int j = 0; j < 5; ++j) cwb[j] = cw[j];
        cwb[5] = cb[0];
    } else if (tid == NL + 1) {
        cwb[6] = c1w[0]; cwb[7] = c1b[0]; cwb[8] = c2w[0]; cwb[9] = c2b[0];
    }

    // load x tile (zero-pad left of t=0; garbage-safe right of T)
    const float* xr = x + (size_t)row * T_LEN;
    #pragma unroll
    for (int p = 0; p < PPT; ++p) {
        const int i = tid + p * NT;
        const int g = t0 - HALO + i;
        hbuf[i] = (g >= 0 && g < T_LEN) ? xr[g] : 0.0f;
    }
    __syncthreads();

    float newh[PPT];
    // initial causal conv, d = 1
    #pragma unroll
    for (int p = 0; p < PPT; ++p) {
        const int i = tid + p * NT;
        float acc = cwb[5];
        #pragma unroll
        for (int j = 0; j < 5; ++j) {
            int idx = i - (4 - j);
            idx = idx < 0 ? 0 : idx;     // left-edge garbage is outside valid region
            acc = fmaf(cwb[j], hbuf[idx], acc);
        }
        newh[p] = acc;
    }
    __syncthreads();
    #pragma unroll
    for (int p = 0; p < PPT; ++p) hbuf[tid + p * NT] = newh[p];

    float skip[PPT];
    #pragma unroll
    for (int p = 0; p < PPT; ++p) skip[p] = 0.0f;

    for (int k = 0; k < NL; ++k) {
        __syncthreads();                  // hbuf for layer k ready
        const int d  = c_dil[k];
        const int o  = k * 14;
        const float f0 = wbuf[o+0], f1 = wbuf[o+1], f2 = wbuf[o+2], f3 = wbuf[o+3], f4 = wbuf[o+4];
        const float fbk = wbuf[o+5];
        const float g0 = wbuf[o+6], g1 = wbuf[o+7], g2 = wbuf[o+8], g3 = wbuf[o+9], g4 = wbuf[o+10];
        const float gbk = wbuf[o+11];
        const float rwk = wbuf[o+12], rbk = wbuf[o+13];
        const int d1 = d, d2 = 2*d, d3 = 3*d, d4 = 4*d;

        #pragma unroll
        for (int p = 0; p < PPT; ++p) {
            const int i = tid + p * NT;
            int i0 = i - d4; i0 = i0 < 0 ? 0 : i0;
            int i1 = i - d3; i1 = i1 < 0 ? 0 : i1;
            int i2 = i - d2; i2 = i2 < 0 ? 0 : i2;
            int i3 = i - d1; i3 = i3 < 0 ? 0 : i3;
            const float v0 = hbuf[i0];
            const float v1 = hbuf[i1];
            const float v2 = hbuf[i2];
            const float v3 = hbuf[i3];
            const float v4 = hbuf[i];

            float af = fbk;
            af = fmaf(f0, v0, af); af = fmaf(f1, v1, af); af = fmaf(f2, v2, af);
            af = fmaf(f3, v3, af); af = fmaf(f4, v4, af);
            float ag = gbk;
            ag = fmaf(g0, v0, ag); ag = fmaf(g1, v1, ag); ag = fmaf(g2, v2, ag);
            ag = fmaf(g3, v3, ag); ag = fmaf(g4, v4, ag);

            // tanh(af) = 1 - 2/(e^{2af}+1)
            const float tf = 1.0f - 2.0f * fast_rcp(__expf(2.0f * af) + 1.0f);
            // sigmoid(ag) = 1/(1+e^{-ag})
            const float sg = fast_rcp(1.0f + __expf(-ag));
            const float z  = tf * sg;
            skip[p] += z;
            newh[p] = fmaf(z, rwk, rbk) + v4;
        }
        __syncthreads();                  // all reads of layer k done
        #pragma unroll
        for (int p = 0; p < PPT; ++p) hbuf[tid + p * NT] = newh[p];
    }

    // epilogue: 1x1 convs + mu-law expand; write v; track block max
    const float w1 = cwb[6], b1 = cwb[7], w2 = cwb[8], b2 = cwb[9];
    float m = -INFINITY;
    float* vr = vout + (size_t)row * T_LEN;
    #pragma unroll
    for (int p = 0; p < PPT; ++p) {
        const int i = tid + p * NT;
        if (i >= HALO) {
            const int t = t0 + i - HALO;
            if (t < T_LEN) {
                float o = fmaf(fmaxf(skip[p], 0.0f), w1, b1);
                o = fmaf(fmaxf(o, 0.0f), w2, b2);
                const float a = fabsf(o);
                float v = (exp2f(8.0f * a) - 1.0f) * (1.0f / 255.0f);
                v = copysignf(v, o);
                vr[t] = v;
                m = fmaxf(m, v);
            }
        }
    }
    #pragma unroll
    for (int off = 32; off >= 1; off >>= 1)
        m = fmaxf(m, __shfl_xor(m, off, 64));
    if ((tid & 63) == 0) redm[tid >> 6] = m;
    __syncthreads();
    if (tid == 0) {
        float mm = redm[0];
        #pragma unroll
        for (int w = 1; w < NT / 64; ++w) mm = fmaxf(mm, redm[w]);
        partmax[blockIdx.x] = mm;
    }
}

// ---------------------------------------------------------------------------
// K2: per 4096-elem chunk: reduce this row's partmax -> rowmax, e = exp(v-max)
// in place, write partial sum.
// ---------------------------------------------------------------------------
__global__ __launch_bounds__(256)
void k_softmax_exp(float* __restrict__ vbuf, const float* __restrict__ partmax,
                   float* __restrict__ partsum)
{
    const int tid = threadIdx.x;
    const int row = blockIdx.x / RB;

    __shared__ float red[4];
    float m = -INFINITY;
    for (int j = tid; j < PB; j += 256) m = fmaxf(m, partmax[row * PB + j]);
    #pragma unroll
    for (int off = 32; off >= 1; off >>= 1)
        m = fmaxf(m, __shfl_xor(m, off, 64));
    if ((tid & 63) == 0) red[tid >> 6] = m;
    __syncthreads();
    const float rm = fmaxf(fmaxf(red[0], red[1]), fmaxf(red[2], red[3]));

    float4* vp = (float4*)(vbuf + (size_t)blockIdx.x * CH);
    float s = 0.0f;
    #pragma unroll
    for (int q = 0; q < 4; ++q) {
        float4 v = vp[tid + q * 256];
        v.x = __expf(v.x - rm); v.y = __expf(v.y - rm);
        v.z = __expf(v.z - rm); v.w = __expf(v.w - rm);
        s += (v.x + v.y) + (v.z + v.w);
        vp[tid + q * 256] = v;
    }
    #pragma unroll
    for (int off = 32; off >= 1; off >>= 1)
        s += __shfl_xor(s, off, 64);
    __shared__ float reds[4];
    if ((tid & 63) == 0) reds[tid >> 6] = s;
    __syncthreads();
    if (tid == 0) partsum[blockIdx.x] = (reds[0] + reds[1]) + (reds[2] + reds[3]);
}

// ---------------------------------------------------------------------------
// K3: per chunk: reduce this row's partsum -> 1/sum, normalize in place.
// ---------------------------------------------------------------------------
__global__ __launch_bounds__(256)
void k_softmax_norm(float* __restrict__ vbuf, const float* __restrict__ partsum)
{
    const int tid = threadIdx.x;
    const int row = blockIdx.x / RB;

    float s = (tid < RB) ? partsum[row * RB + tid] : 0.0f;
    #pragma unroll
    for (int off = 32; off >= 1; off >>= 1)
        s += __shfl_xor(s, off, 64);
    __shared__ float sinv;
    if (tid == 0) sinv = 1.0f / s;
    __syncthreads();
    const float inv = sinv;

    float4* vp = (float4*)(vbuf + (size_t)blockIdx.x * CH);
    #pragma unroll
    for (int q = 0; q < 4; ++q) {
        float4 v = vp[tid + q * 256];
        v.x *= inv; v.y *= inv; v.z *= inv; v.w *= inv;
        vp[tid + q * 256] = v;
    }
}

// ---------------------------------------------------------------------------
extern "C" void kernel_launch(void* const* d_in, const int* in_sizes, int n_in,
                              void* d_out, int out_size, void* d_ws, size_t ws_size,
                              hipStream_t stream)
{
    const float* x   = (const float*)d_in[0];
    const float* cw  = (const float*)d_in[1];
    const float* cb  = (const float*)d_in[2];
    const float* fw  = (const float*)d_in[3];
    const float* fb  = (const float*)d_in[4];
    const float* gw  = (const float*)d_in[5];
    const float* gb  = (const float*)d_in[6];
    const float* rw  = (const float*)d_in[7];
    const float* rb  = (const float*)d_in[8];
    const float* c1w = (const float*)d_in[9];
    const float* c1b = (const float*)d_in[10];
    const float* c2w = (const float*)d_in[11];
    const float* c2b = (const float*)d_in[12];

    float* vout    = (float*)d_out;
    float* partmax = (float*)d_ws;            // NROW*PB = 600 floats
    float* partsum = partmax + 1024;          // NB2 = 512 floats

    k_wavenet<<<NROW * PB, NT, 0, stream>>>(x, cw, cb, fw, fb, gw, gb, rw, rb,
                                            c1w, c1b, c2w, c2b, vout, partmax);
    k_softmax_exp<<<NB2, 256, 0, stream>>>(vout, partmax, partsum);
    k_softmax_norm<<<NB2, 256, 0, stream>>>(vout, partsum);
}

// Round 2
// 169.829 us; speedup vs baseline: 1.1637x; 1.1637x over previous
//
#include <hip/hip_runtime.h>
#include <cmath>

#define T_LEN 262144
#define NROW 8
#define NL 30
#define NT 512
#define PPT 7
#define EXT (NT * PPT)              /* 3584 */
#define HALO 576
#define TILE (EXT - HALO)           /* 3008 */
#define PB ((T_LEN + TILE - 1) / TILE)   /* 88 tiles per row */
#define PAD 32
#define CH 4096                     /* elements per softmax chunk */
#define RB (T_LEN / CH)             /* 64 chunks per row */
#define NB2 (NROW * RB)             /* 512 */

#define LOG2E_2 2.885390082f        /* 2*log2(e) */
#define NLOG2E  -1.4426950409f      /* -log2(e) */

__device__ __forceinline__ float fast_rcp(float x) { return __builtin_amdgcn_rcpf(x); }

// One gated residual layer, dilation D compile-time so tap reads become
// ds_read with immediate offsets. h (center tap) stays in registers.
template<int D>
__device__ __forceinline__ void layer_step(
    int k,
    const float* __restrict__ fw, const float* __restrict__ fb,
    const float* __restrict__ gw, const float* __restrict__ gb,
    const float* __restrict__ rw, const float* __restrict__ rb,
    float* __restrict__ hb, float (&h)[PPT], float (&skip)[PPT],
    int tid, bool writeback)
{
    // uniform (scalar-pipe) weight loads
    const float f0 = fw[k*5+0], f1 = fw[k*5+1], f2 = fw[k*5+2], f3 = fw[k*5+3], f4 = fw[k*5+4];
    const float fbk = fb[k];
    const float g0 = gw[k*5+0], g1 = gw[k*5+1], g2 = gw[k*5+2], g3 = gw[k*5+3], g4 = gw[k*5+4];
    const float gbk = gb[k];
    const float rwk = rw[k], rbk = rb[k];

    #pragma unroll
    for (int p = 0; p < PPT; ++p) {
        const int i = tid + p * NT;
        const float v0 = hb[i - 4*D];
        const float v1 = hb[i - 3*D];
        const float v2 = hb[i - 2*D];
        const float v3 = hb[i - D];
        const float v4 = h[p];

        float af = fbk;
        af = fmaf(f0, v0, af); af = fmaf(f1, v1, af); af = fmaf(f2, v2, af);
        af = fmaf(f3, v3, af); af = fmaf(f4, v4, af);
        float ag = gbk;
        ag = fmaf(g0, v0, ag); ag = fmaf(g1, v1, ag); ag = fmaf(g2, v2, ag);
        ag = fmaf(g3, v3, ag); ag = fmaf(g4, v4, ag);

        const float tf = fmaf(-2.0f, fast_rcp(exp2f(af * LOG2E_2) + 1.0f), 1.0f);
        const float sg = fast_rcp(1.0f + exp2f(ag * NLOG2E));
        const float z  = tf * sg;
        skip[p] += z;
        h[p] = fmaf(z, rwk, rbk) + v4;
    }
    if (writeback) {
        __syncthreads();               // all reads of this layer's input done
        #pragma unroll
        for (int p = 0; p < PPT; ++p) hb[tid + p * NT] = h[p];
        __syncthreads();               // writes visible for next layer
    }
}

// ---------------------------------------------------------------------------
__global__ __launch_bounds__(NT)
void k_wavenet(const float* __restrict__ x,
               const float* __restrict__ cw,  const float* __restrict__ cb,
               const float* __restrict__ fw,  const float* __restrict__ fb,
               const float* __restrict__ gw,  const float* __restrict__ gb,
               const float* __restrict__ rw,  const float* __restrict__ rb,
               const float* __restrict__ c1w, const float* __restrict__ c1b,
               const float* __restrict__ c2w, const float* __restrict__ c2b,
               float* __restrict__ vout, float* __restrict__ partmax)
{
    __shared__ float hraw[PAD + EXT];   // 14.5 KB
    __shared__ float redm[NT / 64];
    float* hb = hraw + PAD;

    const int tid  = threadIdx.x;
    const int row  = blockIdx.x / PB;
    const int tile = blockIdx.x % PB;
    const int t0   = tile * TILE;

    if (tid < PAD) hraw[tid] = 0.0f;    // left pad: virtual positions < tile start

    const float* xr = x + (size_t)row * T_LEN;
    float h[PPT], skip[PPT];
    #pragma unroll
    for (int p = 0; p < PPT; ++p) {
        const int i = tid + p * NT;
        const int g = t0 - HALO + i;
        const float v = (g >= 0 && g < T_LEN) ? xr[g] : 0.0f;
        hb[i] = v; h[p] = v; skip[p] = 0.0f;
    }
    __syncthreads();

    // initial causal conv, d=1
    {
        const float w0 = cw[0], w1 = cw[1], w2 = cw[2], w3 = cw[3], w4 = cw[4];
        const float b  = cb[0];
        #pragma unroll
        for (int p = 0; p < PPT; ++p) {
            const int i = tid + p * NT;
            float acc = b;
            acc = fmaf(w0, hb[i-4], acc);
            acc = fmaf(w1, hb[i-3], acc);
            acc = fmaf(w2, hb[i-2], acc);
            acc = fmaf(w3, hb[i-1], acc);
            acc = fmaf(w4, h[p],    acc);
            h[p] = acc;
        }
        __syncthreads();
        #pragma unroll
        for (int p = 0; p < PPT; ++p) hb[tid + p * NT] = h[p];
        __syncthreads();
    }

    // 30 layers: d = 1, then [2,4,8,6] x7, then 2
    layer_step<1>(0, fw, fb, gw, gb, rw, rb, hb, h, skip, tid, true);
    int k = 1;
    #pragma unroll 1
    for (int c = 0; c < 7; ++c) {
        layer_step<2>(k+0, fw, fb, gw, gb, rw, rb, hb, h, skip, tid, true);
        layer_step<4>(k+1, fw, fb, gw, gb, rw, rb, hb, h, skip, tid, true);
        layer_step<8>(k+2, fw, fb, gw, gb, rw, rb, hb, h, skip, tid, true);
        layer_step<6>(k+3, fw, fb, gw, gb, rw, rb, hb, h, skip, tid, true);
        k += 4;
    }
    layer_step<2>(29, fw, fb, gw, gb, rw, rb, hb, h, skip, tid, false);

    // epilogue: two 1x1 conv+relu, mu-law expand, write v, track block max
    const float w1 = c1w[0], b1 = c1b[0], w2 = c2w[0], b2 = c2b[0];
    float m = -INFINITY;
    float* vr = vout + (size_t)row * T_LEN;
    #pragma unroll
    for (int p = 0; p < PPT; ++p) {
        const int i = tid + p * NT;
        if (i >= HALO) {
            const int t = t0 + i - HALO;
            if (t < T_LEN) {
                float o = fmaf(fmaxf(skip[p], 0.0f), w1, b1);
                o = fmaf(fmaxf(o, 0.0f), w2, b2);
                const float a = fabsf(o);
                float v = (exp2f(8.0f * a) - 1.0f) * (1.0f / 255.0f);
                v = copysignf(v, o);
                vr[t] = v;
                m = fmaxf(m, v);
            }
        }
    }
    #pragma unroll
    for (int off = 32; off >= 1; off >>= 1)
        m = fmaxf(m, __shfl_xor(m, off, 64));
    if ((tid & 63) == 0) redm[tid >> 6] = m;
    __syncthreads();
    if (tid == 0) {
        float mm = redm[0];
        #pragma unroll
        for (int w = 1; w < NT / 64; ++w) mm = fmaxf(mm, redm[w]);
        partmax[blockIdx.x] = mm;
    }
}

// ---------------------------------------------------------------------------
__global__ __launch_bounds__(256)
void k_softmax_exp(float* __restrict__ vbuf, const float* __restrict__ partmax,
                   float* __restrict__ partsum)
{
    const int tid = threadIdx.x;
    const int row = blockIdx.x / RB;

    __shared__ float red[4];
    float m = -INFINITY;
    for (int j = tid; j < PB; j += 256) m = fmaxf(m, partmax[row * PB + j]);
    #pragma unroll
    for (int off = 32; off >= 1; off >>= 1)
        m = fmaxf(m, __shfl_xor(m, off, 64));
    if ((tid & 63) == 0) red[tid >> 6] = m;
    __syncthreads();
    const float rm = fmaxf(fmaxf(red[0], red[1]), fmaxf(red[2], red[3]));

    float4* vp = (float4*)(vbuf + (size_t)blockIdx.x * CH);
    float s = 0.0f;
    #pragma unroll
    for (int q = 0; q < 4; ++q) {
        float4 v = vp[tid + q * 256];
        v.x = __expf(v.x - rm); v.y = __expf(v.y - rm);
        v.z = __expf(v.z - rm); v.w = __expf(v.w - rm);
        s += (v.x + v.y) + (v.z + v.w);
        vp[tid + q * 256] = v;
    }
    #pragma unroll
    for (int off = 32; off >= 1; off >>= 1)
        s += __shfl_xor(s, off, 64);
    __shared__ float reds[4];
    if ((tid & 63) == 0) reds[tid >> 6] = s;
    __syncthreads();
    if (tid == 0) partsum[blockIdx.x] = (reds[0] + reds[1]) + (reds[2] + reds[3]);
}

// ---------------------------------------------------------------------------
__global__ __launch_bounds__(256)
void k_softmax_norm(float* __restrict__ vbuf, const float* __restrict__ partsum)
{
    const int tid = threadIdx.x;
    const int row = blockIdx.x / RB;

    float s = (tid < RB) ? partsum[row * RB + tid] : 0.0f;
    #pragma unroll
    for (int off = 32; off >= 1; off >>= 1)
        s += __shfl_xor(s, off, 64);
    __shared__ float sinv;
    if (tid == 0) sinv = 1.0f / s;
    __syncthreads();
    const float inv = sinv;

    float4* vp = (float4*)(vbuf + (size_t)blockIdx.x * CH);
    #pragma unroll
    for (int q = 0; q < 4; ++q) {
        float4 v = vp[tid + q * 256];
        v.x *= inv; v.y *= inv; v.z *= inv; v.w *= inv;
        vp[tid + q * 256] = v;
    }
}

// ---------------------------------------------------------------------------
extern "C" void kernel_launch(void* const* d_in, const int* in_sizes, int n_in,
                              void* d_out, int out_size, void* d_ws, size_t ws_size,
                              hipStream_t stream)
{
    const float* x   = (const float*)d_in[0];
    const float* cw  = (const float*)d_in[1];
    const float* cb  = (const float*)d_in[2];
    const float* fw  = (const float*)d_in[3];
    const float* fb  = (const float*)d_in[4];
    const float* gw  = (const float*)d_in[5];
    const float* gb  = (const float*)d_in[6];
    const float* rw  = (const float*)d_in[7];
    const float* rb  = (const float*)d_in[8];
    const float* c1w = (const float*)d_in[9];
    const float* c1b = (const float*)d_in[10];
    const float* c2w = (const float*)d_in[11];
    const float* c2b = (const float*)d_in[12];

    float* vout    = (float*)d_out;
    float* partmax = (float*)d_ws;            // NROW*PB = 704 floats
    float* partsum = partmax + 1024;          // NB2 = 512 floats

    k_wavenet<<<NROW * PB, NT, 0, stream>>>(x, cw, cb, fw, fb, gw, gb, rw, rb,
                                            c1w, c1b, c2w, c2b, vout, partmax);
    k_softmax_exp<<<NB2, 256, 0, stream>>>(vout, partmax, partsum);
    k_softmax_norm<<<NB2, 256, 0, stream>>>(vout, partsum);
}